// Round 5
// baseline (1528.755 us; speedup 1.0000x reference)
//
#include <hip/hip_runtime.h>
#include <math.h>

#define BDIM 64
#define NNODE 128
#define DLAT 80
#define NHEAD 8
#define DH 64
#define INNER 512
#define FFD 160
#define DEPTH 24
#define MROWS (BDIM * NNODE)   // 8192

using bf16x8 = __attribute__((ext_vector_type(8))) short;
using f32x4  = __attribute__((ext_vector_type(4))) float;

#define MFMA(a, b, c) __builtin_amdgcn_mfma_f32_16x16x32_bf16((a), (b), (c), 0, 0, 0)

static __device__ __forceinline__ short f2bf(float f) {
    union { float f; unsigned u; } v; v.f = f;
    unsigned r = v.u + 0x7fffu + ((v.u >> 16) & 1u);   // RNE
    return (short)(r >> 16);
}

// ---------------------------------------------------------------------------
// Weight convert + transpose + zero-pad K: out[l][n][kp] = bf16(in[l][k][n])
// ---------------------------------------------------------------------------
__global__ __launch_bounds__(256) void wconv_kernel(
    const float* __restrict__ in, short* __restrict__ out, int K, int N, int Kp)
{
    __shared__ float t[64][65];
    int L = blockIdx.z;
    const float* src = in + (size_t)L * K * N;
    short* dst = out + (size_t)L * N * Kp;
    int n0 = blockIdx.x * 64, k0 = blockIdx.y * 64;
    int tx = threadIdx.x & 63, ty = threadIdx.x >> 6;
    for (int ki = ty; ki < 64; ki += 4) {
        int k = k0 + ki, n = n0 + tx;
        t[ki][tx] = (k < K && n < N) ? src[(size_t)k * N + n] : 0.f;
    }
    __syncthreads();
    for (int ni = ty; ni < 64; ni += 4) {
        int n = n0 + ni, k = k0 + tx;
        if (n < N && k < Kp) dst[(size_t)n * Kp + k] = f2bf(t[tx][ni]);
    }
}

// ---------------------------------------------------------------------------
// Graph structural bias
// ---------------------------------------------------------------------------
__global__ __launch_bounds__(256) void bias_kernel(
    const int* __restrict__ spp, const int* __restrict__ ei,
    const float* __restrict__ edge_emb, const float* __restrict__ edw,
    const float* __restrict__ sp_emb, float* __restrict__ biasb)
{
    __shared__ float ee[64], ew[20], se[40];
    int tid = threadIdx.x;
    if (tid < 64) ee[tid] = edge_emb[tid];
    if (tid < 20) ew[tid] = edw[tid];
    if (tid < 40) se[tid] = sp_emb[tid];
    __syncthreads();

    int idx = blockIdx.x * 256 + tid;
    int spv = spp[idx];
    float spb = se[spv];
    int sp = min(20, max(1, spv - 1));

    const int4* p = (const int4*)(ei + (size_t)idx * 60);
    int e[60];
#pragma unroll
    for (int t = 0; t < 15; ++t) {
        int4 v = p[t];
        e[4*t+0] = v.x; e[4*t+1] = v.y; e[4*t+2] = v.z; e[4*t+3] = v.w;
    }
    float acc = 0.f;
#pragma unroll
    for (int m = 0; m < 20; ++m) {
        float s = ee[e[3*m]] + ee[e[3*m+1]] + ee[e[3*m+2]];
        acc += s * ew[m];
    }
    biasb[idx] = acc * (1.0f/3.0f) / (float)sp + spb;
}

// ---------------------------------------------------------------------------
// Node embeddings
// ---------------------------------------------------------------------------
__global__ __launch_bounds__(256) void node_emb_kernel(
    const int* __restrict__ xn, const int* __restrict__ ind, const int* __restrict__ outd,
    const float* __restrict__ ae, const float* __restrict__ ie, const float* __restrict__ oe,
    float* __restrict__ x)
{
    int idx = blockIdx.x * 256 + threadIdx.x;
    int e = idx / DLAT, d = idx % DLAT;
    x[idx] = ae[xn[e]*DLAT + d] + ie[ind[e]*DLAT + d] + oe[outd[e]*DLAT + d];
}

// ---------------------------------------------------------------------------
// Standalone LN1 (layer 0 only): lnx[row][96] = bf16(LN(x)*g+b), pad 80..95=0
// grid 64 x 256 threads, 2 threads/row.
// ---------------------------------------------------------------------------
__global__ __launch_bounds__(256) void ln1_kernel(
    const float* __restrict__ x, const float* __restrict__ g,
    const float* __restrict__ be, short* __restrict__ lnx)
{
    int row = blockIdx.x * 128 + (threadIdx.x >> 1), sub = threadIdx.x & 1;
    const float* xr = x + (size_t)row * DLAT + sub * 40;
    float4 v[10];
#pragma unroll
    for (int i = 0; i < 10; ++i) v[i] = *(const float4*)(xr + i * 4);
    float s = 0.f;
#pragma unroll
    for (int i = 0; i < 10; ++i) s += v[i].x + v[i].y + v[i].z + v[i].w;
    s += __shfl_xor(s, 1);
    float mean = s * 0.0125f;
    float var = 0.f;
#pragma unroll
    for (int i = 0; i < 10; ++i) {
        float d;
        d = v[i].x - mean; var += d * d;
        d = v[i].y - mean; var += d * d;
        d = v[i].z - mean; var += d * d;
        d = v[i].w - mean; var += d * d;
    }
    var += __shfl_xor(var, 1);
    float rstd = 1.0f / sqrtf(var * 0.0125f + 1e-5f);
    short* dst = lnx + (size_t)row * 96 + sub * 40;
#pragma unroll
    for (int i = 0; i < 10; ++i) {
        int c = sub * 40 + i * 4;
        float4 g4 = *(const float4*)(g + c);
        float4 b4 = *(const float4*)(be + c);
        short4 o;
        o.x = f2bf((v[i].x - mean) * rstd * g4.x + b4.x);
        o.y = f2bf((v[i].y - mean) * rstd * g4.y + b4.y);
        o.z = f2bf((v[i].z - mean) * rstd * g4.z + b4.z);
        o.w = f2bf((v[i].w - mean) * rstd * g4.w + b4.w);
        *(short4*)(dst + i * 4) = o;
    }
    short4 z4; z4.x = z4.y = z4.z = z4.w = 0;
    *(short4*)(lnx + (size_t)row * 96 + 80 + sub * 8) = z4;
    *(short4*)(lnx + (size_t)row * 96 + 84 + sub * 8) = z4;
}

// ---------------------------------------------------------------------------
// Attention kernel: one block per (b, head). 512 threads = 8 waves.
// Reads lnx (bf16, global) as A directly. Q/K/V -> QK^T+bias -> softmax -> PV.
// Grid 512, 2 blocks/CU -> 4 waves/SIMD. LDS 54,272 B.
//   qh@0 [128][72]; kh@9216 [128][72]; vth@18432 [64][136]
//   ph@0 [128][136] (overlay qh+kh); ot@18432 [128][68] (overlay vth)
// ---------------------------------------------------------------------------
__global__ __launch_bounds__(512, 4) void attn2_kernel(
    const short* __restrict__ lnx, const float* __restrict__ biasb,
    const short* __restrict__ Wq_t, const short* __restrict__ Wkv_t,
    short* __restrict__ obuf)
{
    extern __shared__ short smem[];
    short* qh  = smem;           // [128][72]
    short* kh  = smem + 9216;    // [128][72]
    short* vth = smem + 18432;   // [64][136]
    short* ph  = smem;           // [128][136] overlay
    short* ot  = smem + 18432;   // [128][68]  overlay

    int tid = threadIdx.x;
    int lane = tid & 63, w = tid >> 6, l15 = lane & 15, lk = lane >> 4;
    int b = blockIdx.x >> 3, h = blockIdx.x & 7;

    // ---- bias loads issued early (consumed after QK^T) ----
    float breg[8][4];
    {
        const float* bp = biasb + ((size_t)b * NNODE + w * 16) * NNODE;
#pragma unroll
        for (int jf = 0; jf < 8; ++jf)
#pragma unroll
            for (int r = 0; r < 4; ++r)
                breg[jf][r] = bp[(lk * 4 + r) * NNODE + jf * 16 + l15];
    }

    // ---- Q,K,V for this head; wave w owns rows w*16..w*16+15 ----
    {
        const short* lb = lnx + (size_t)b * NNODE * 96;
        bf16x8 a[3];
#pragma unroll
        for (int ss = 0; ss < 3; ++ss)
            a[ss] = *(const bf16x8*)(lb + (w * 16 + l15) * 96 + ss * 32 + lk * 8);

        // Q -> qh
        {
            f32x4 acc[4] = {};
#pragma unroll
            for (int ss = 0; ss < 3; ++ss)
#pragma unroll
                for (int nf = 0; nf < 4; ++nf) {
                    bf16x8 bv = *(const bf16x8*)(Wq_t + (size_t)(h * 64 + nf * 16 + l15) * 96 + ss * 32 + lk * 8);
                    acc[nf] = MFMA(a[ss], bv, acc[nf]);
                }
#pragma unroll
            for (int nf = 0; nf < 4; ++nf)
#pragma unroll
                for (int r = 0; r < 4; ++r)
                    qh[(w * 16 + lk * 4 + r) * 72 + nf * 16 + l15] = f2bf(acc[nf][r]);
        }
        // K -> kh
        {
            f32x4 acc[4] = {};
#pragma unroll
            for (int ss = 0; ss < 3; ++ss)
#pragma unroll
                for (int nf = 0; nf < 4; ++nf) {
                    bf16x8 bv = *(const bf16x8*)(Wkv_t + (size_t)(h * 64 + nf * 16 + l15) * 96 + ss * 32 + lk * 8);
                    acc[nf] = MFMA(a[ss], bv, acc[nf]);
                }
#pragma unroll
            for (int nf = 0; nf < 4; ++nf)
#pragma unroll
                for (int r = 0; r < 4; ++r)
                    kh[(w * 16 + lk * 4 + r) * 72 + nf * 16 + l15] = f2bf(acc[nf][r]);
        }
        // V -> vth (transposed)
        {
            f32x4 acc[4] = {};
#pragma unroll
            for (int ss = 0; ss < 3; ++ss)
#pragma unroll
                for (int nf = 0; nf < 4; ++nf) {
                    bf16x8 bv = *(const bf16x8*)(Wkv_t + (size_t)(INNER + h * 64 + nf * 16 + l15) * 96 + ss * 32 + lk * 8);
                    acc[nf] = MFMA(a[ss], bv, acc[nf]);
                }
#pragma unroll
            for (int nf = 0; nf < 4; ++nf)
#pragma unroll
                for (int r = 0; r < 4; ++r)
                    vth[(nf * 16 + l15) * 136 + w * 16 + lk * 4 + r] = f2bf(acc[nf][r]);
        }
    }
    __syncthreads();

    // ---- QK^T ----
    f32x4 sc[8] = {};
#pragma unroll
    for (int ss = 0; ss < 2; ++ss) {
        bf16x8 qa = *(const bf16x8*)(qh + (w * 16 + l15) * 72 + ss * 32 + lk * 8);
#pragma unroll
        for (int jf = 0; jf < 8; ++jf) {
            bf16x8 bv = *(const bf16x8*)(kh + (jf * 16 + l15) * 72 + ss * 32 + lk * 8);
            sc[jf] = MFMA(qa, bv, sc[jf]);
        }
    }
    __syncthreads();   // all qh/kh reads done before ph overlay writes

    // ---- softmax + P -> LDS ----
    float rinv[4];
#pragma unroll
    for (int r = 0; r < 4; ++r) {
        float sv[8];
#pragma unroll
        for (int jf = 0; jf < 8; ++jf) sv[jf] = sc[jf][r] * 0.125f + breg[jf][r];
        float mx = sv[0];
#pragma unroll
        for (int jf = 1; jf < 8; ++jf) mx = fmaxf(mx, sv[jf]);
        mx = fmaxf(mx, __shfl_xor(mx, 1));
        mx = fmaxf(mx, __shfl_xor(mx, 2));
        mx = fmaxf(mx, __shfl_xor(mx, 4));
        mx = fmaxf(mx, __shfl_xor(mx, 8));
        float e[8], sum = 0.f;
#pragma unroll
        for (int jf = 0; jf < 8; ++jf) { e[jf] = __expf(sv[jf] - mx); sum += e[jf]; }
        sum += __shfl_xor(sum, 1);
        sum += __shfl_xor(sum, 2);
        sum += __shfl_xor(sum, 4);
        sum += __shfl_xor(sum, 8);
        rinv[r] = 1.0f / sum;
        int row = w * 16 + lk * 4 + r;
#pragma unroll
        for (int jf = 0; jf < 8; ++jf)
            ph[row * 136 + jf * 16 + l15] = f2bf(e[jf]);
    }
    __syncthreads();

    // ---- PV ----
    f32x4 o[4] = {};
#pragma unroll
    for (int ks = 0; ks < 4; ++ks) {
        bf16x8 pa = *(const bf16x8*)(ph + (w * 16 + l15) * 136 + ks * 32 + lk * 8);
#pragma unroll
        for (int nf = 0; nf < 4; ++nf) {
            bf16x8 bv = *(const bf16x8*)(vth + (nf * 16 + l15) * 136 + ks * 32 + lk * 8);
            o[nf] = MFMA(pa, bv, o[nf]);
        }
    }
    __syncthreads();   // vth reads done before ot overlay writes

    // ---- scaled output -> ot ----
#pragma unroll
    for (int nf = 0; nf < 4; ++nf)
#pragma unroll
        for (int r = 0; r < 4; ++r)
            ot[(w * 16 + lk * 4 + r) * 68 + nf * 16 + l15] = f2bf(o[nf][r] * rinv[r]);
    __syncthreads();

    // ---- coalesced store: each thread 32B of one row ----
    {
        int row = tid >> 2, q4 = tid & 3;
        const short* src = ot + row * 68 + q4 * 16;
        short* dst = obuf + ((size_t)b * NNODE + row) * INNER + h * 64 + q4 * 16;
#pragma unroll
        for (int qq = 0; qq < 4; ++qq)
            *(uint2*)(dst + qq * 4) = *(const uint2*)(src + qq * 4);
    }
}

// ---------------------------------------------------------------------------
// Tail kernel: one block per (b, quarter), 512 threads = 8 waves.
// obuf@Wo + bo + resid -> LN2 -> FF1+GELU -> FF2 + b2 + resid -> xout,
// then fused LN1 of next layer -> lnx. A-fragments direct from global obuf.
// ---------------------------------------------------------------------------
__global__ __launch_bounds__(512, 2) void tail2_kernel(
    const short* __restrict__ obuf, const float* __restrict__ xin,
    const short* __restrict__ Wo_t, const float* __restrict__ boL,
    const float* __restrict__ g2, const float* __restrict__ be2,
    const short* __restrict__ W1_t, const float* __restrict__ b1L,
    const short* __restrict__ W2_t, const float* __restrict__ b2L,
    float* __restrict__ xout,
    const float* __restrict__ g1n, const float* __restrict__ be1n,
    short* __restrict__ lnx)
{
    __shared__ float xmid[32 * 84];    // 10,752 B
    __shared__ short h2s[32 * 104];    //  6,656 B
    __shared__ short ffhs[32 * 168];   // 10,752 B

    int tid = threadIdx.x;
    int lane = tid & 63, w = tid >> 6, l15 = lane & 15, lk = lane >> 4;
    int b = blockIdx.x >> 2, qq = blockIdx.x & 3;
    int R0 = qq * 32;
    int wr = w >> 2, wn = w & 3;

    int n0_5 = (wn == 0) ? 0 : (wn + 1);      // {0,2,3,4}
    int nc_5 = (wn == 0) ? 2 : 1;
    int n0_10 = (wn < 2) ? wn * 3 : 6 + (wn - 2) * 2;  // {0,3,6,8}
    int nc_10 = (wn < 2) ? 3 : 2;

    // ---- O-proj + bo + residual -> xmid (A direct from global obuf) ----
    {
        const short* og = obuf + ((size_t)b * NNODE + R0) * INNER;
        f32x4 acc[2] = {};
#pragma unroll 4
        for (int ks = 0; ks < 16; ++ks) {
            bf16x8 aa = *(const bf16x8*)(og + (wr * 16 + l15) * INNER + lk * 8 + ks * 32);
#pragma unroll
            for (int j = 0; j < 2; ++j)
                if (j < nc_5) {
                    bf16x8 bv = *(const bf16x8*)(Wo_t + (size_t)((n0_5 + j) * 16 + l15) * INNER + lk * 8 + ks * 32);
                    acc[j] = MFMA(aa, bv, acc[j]);
                }
        }
#pragma unroll
        for (int j = 0; j < 2; ++j)
            if (j < nc_5)
#pragma unroll
                for (int r = 0; r < 4; ++r) {
                    int row = wr * 16 + lk * 4 + r, col = (n0_5 + j) * 16 + l15;
                    xmid[row * 84 + col] = acc[j][r] + boL[col] +
                        xin[((size_t)b * NNODE + R0 + row) * DLAT + col];
                }
    }
    __syncthreads();

    // ---- LN2 -> h2s (16 threads/row) ----
    {
        int row = tid >> 4, sub = tid & 15;
        float v[5];
#pragma unroll
        for (int e = 0; e < 5; ++e) v[e] = xmid[row * 84 + sub * 5 + e];
        float s = v[0] + v[1] + v[2] + v[3] + v[4];
        s += __shfl_xor(s, 1); s += __shfl_xor(s, 2);
        s += __shfl_xor(s, 4); s += __shfl_xor(s, 8);
        float mean = s * 0.0125f;
        float var = 0.f;
#pragma unroll
        for (int e = 0; e < 5; ++e) { float d = v[e] - mean; var += d * d; }
        var += __shfl_xor(var, 1); var += __shfl_xor(var, 2);
        var += __shfl_xor(var, 4); var += __shfl_xor(var, 8);
        float rstd = 1.0f / sqrtf(var * 0.0125f + 1e-5f);
#pragma unroll
        for (int e = 0; e < 5; ++e) {
            int c = sub * 5 + e;
            h2s[row * 104 + c] = f2bf((v[e] - mean) * rstd * g2[c] + be2[c]);
        }
        if (sub < 4) {
            short4 z4; z4.x = z4.y = z4.z = z4.w = 0;
            *(short4*)(h2s + row * 104 + 80 + sub * 4) = z4;
        }
    }
    __syncthreads();

    // ---- FF1 + GELU -> ffhs ----
    {
        f32x4 acc[3] = {};
#pragma unroll
        for (int ss = 0; ss < 3; ++ss) {
            bf16x8 aa = *(const bf16x8*)(h2s + (wr * 16 + l15) * 104 + lk * 8 + ss * 32);
#pragma unroll
            for (int j = 0; j < 3; ++j)
                if (j < nc_10) {
                    bf16x8 bv = *(const bf16x8*)(W1_t + (size_t)((n0_10 + j) * 16 + l15) * 96 + lk * 8 + ss * 32);
                    acc[j] = MFMA(aa, bv, acc[j]);
                }
        }
#pragma unroll
        for (int j = 0; j < 3; ++j)
            if (j < nc_10)
#pragma unroll
                for (int r = 0; r < 4; ++r) {
                    int row = wr * 16 + lk * 4 + r, c = (n0_10 + j) * 16 + l15;
                    float vv = acc[j][r] + b1L[c];
                    vv = 0.5f * vv * (1.0f + erff(vv * 0.70710678118654752f));
                    ffhs[row * 168 + c] = f2bf(vv);
                }
    }
    __syncthreads();

    // ---- FF2 + b2 + residual -> xout (and xmid in place) ----
    {
        f32x4 acc[2] = {};
#pragma unroll
        for (int ks = 0; ks < 5; ++ks) {
            bf16x8 aa = *(const bf16x8*)(ffhs + (wr * 16 + l15) * 168 + lk * 8 + ks * 32);
#pragma unroll
            for (int j = 0; j < 2; ++j)
                if (j < nc_5) {
                    bf16x8 bv = *(const bf16x8*)(W2_t + (size_t)((n0_5 + j) * 16 + l15) * FFD + lk * 8 + ks * 32);
                    acc[j] = MFMA(aa, bv, acc[j]);
                }
        }
#pragma unroll
        for (int j = 0; j < 2; ++j)
            if (j < nc_5)
#pragma unroll
                for (int r = 0; r < 4; ++r) {
                    int row = wr * 16 + lk * 4 + r, col = (n0_5 + j) * 16 + l15;
                    float vv = acc[j][r] + b2L[col] + xmid[row * 84 + col];
                    xout[((size_t)b * NNODE + R0 + row) * DLAT + col] = vv;
                    xmid[row * 84 + col] = vv;
                }
    }
    __syncthreads();

    // ---- fused LN1 of next layer -> lnx ----
    if (g1n) {
        int row = tid >> 4, sub = tid & 15;
        float v[5];
#pragma unroll
        for (int e = 0; e < 5; ++e) v[e] = xmid[row * 84 + sub * 5 + e];
        float s = v[0] + v[1] + v[2] + v[3] + v[4];
        s += __shfl_xor(s, 1); s += __shfl_xor(s, 2);
        s += __shfl_xor(s, 4); s += __shfl_xor(s, 8);
        float mean = s * 0.0125f;
        float var = 0.f;
#pragma unroll
        for (int e = 0; e < 5; ++e) { float d = v[e] - mean; var += d * d; }
        var += __shfl_xor(var, 1); var += __shfl_xor(var, 2);
        var += __shfl_xor(var, 4); var += __shfl_xor(var, 8);
        float rstd = 1.0f / sqrtf(var * 0.0125f + 1e-5f);
        short* lr = lnx + ((size_t)b * NNODE + R0 + row) * 96;
#pragma unroll
        for (int e = 0; e < 5; ++e) {
            int c = sub * 5 + e;
            lr[c] = f2bf((v[e] - mean) * rstd * g1n[c] + be1n[c]);
        }
        if (sub < 8) { lr[80 + sub * 2] = 0; lr[81 + sub * 2] = 0; }
    }
}

// ---------------------------------------------------------------------------
// Final: mean over nodes -> LN -> @Wf + bf
// ---------------------------------------------------------------------------
__global__ __launch_bounds__(128) void final_kernel(
    const float* __restrict__ x, const float* __restrict__ g, const float* __restrict__ bta,
    const float* __restrict__ Wf, const float* __restrict__ bf, float* __restrict__ out)
{
    int bb = blockIdx.x;
    int t = threadIdx.x;
    __shared__ float pd[DLAT];
    __shared__ float red[2];
    __shared__ float rbuf[128];

    if (t < DLAT) {
        float s = 0.f;
        for (int n = 0; n < NNODE; ++n) s += x[((size_t)bb * NNODE + n) * DLAT + t];
        pd[t] = s * (1.0f / NNODE);
    }
    __syncthreads();
    if (t == 0) {
        float m = 0.f;
        for (int k = 0; k < DLAT; ++k) m += pd[k];
        m /= DLAT;
        float v = 0.f;
        for (int k = 0; k < DLAT; ++k) { float d = pd[k] - m; v += d * d; }
        v /= DLAT;
        red[0] = m; red[1] = 1.0f / sqrtf(v + 1e-5f);
    }
    __syncthreads();
    float contrib = 0.f;
    if (t < DLAT)
        contrib = ((pd[t] - red[0]) * red[1] * g[t] + bta[t]) * Wf[t];
    rbuf[t] = contrib;
    __syncthreads();
    if (t == 0) {
        float s = 0.f;
        for (int k = 0; k < DLAT; ++k) s += rbuf[k];
        out[bb] = s + bf[0];
    }
}

// ---------------------------------------------------------------------------
extern "C" void kernel_launch(void* const* d_in, const int* in_sizes, int n_in,
                              void* d_out, int out_size, void* d_ws, size_t ws_size,
                              hipStream_t stream)
{
    const int*   spatial_pos = (const int*)  d_in[0];
    const int*   edge_input  = (const int*)  d_in[1];
    const int*   x_nodes     = (const int*)  d_in[2];
    const int*   indeg       = (const int*)  d_in[3];
    const int*   outdeg      = (const int*)  d_in[4];
    const float* atom_emb    = (const float*)d_in[5];
    const float* indeg_emb   = (const float*)d_in[6];
    const float* outdeg_emb  = (const float*)d_in[7];
    const float* edge_emb    = (const float*)d_in[8];
    const float* edge_dis_w  = (const float*)d_in[9];
    const float* spatial_emb = (const float*)d_in[10];
    const float* ln1_g = (const float*)d_in[11];
    const float* ln1_b = (const float*)d_in[12];
    const float* Wq    = (const float*)d_in[13];
    const float* Wkv   = (const float*)d_in[14];
    const float* Wo    = (const float*)d_in[15];
    const float* bo    = (const float*)d_in[16];
    const float* ln2_g = (const float*)d_in[17];
    const float* ln2_b = (const float*)d_in[18];
    const float* W1    = (const float*)d_in[19];
    const float* b1    = (const float*)d_in[20];
    const float* W2    = (const float*)d_in[21];
    const float* b2    = (const float*)d_in[22];
    const float* lnf_g = (const float*)d_in[23];
    const float* lnf_b = (const float*)d_in[24];
    const float* Wf    = (const float*)d_in[25];
    const float* bf    = (const float*)d_in[26];

    char* wsb = (char*)d_ws;
    float* biasb = (float*)(wsb + 0);           //  4,194,304
    float* x0    = (float*)(wsb + 4194304);     //  2,621,440
    float* x1    = (float*)(wsb + 6815744);     //  2,621,440
    short* obuf  = (short*)(wsb + 9437184);     //  8,388,608
    short* Wq_t  = (short*)(wsb + 17825792);    //  2,359,296  [512][96]/layer
    short* Wkv_t = (short*)(wsb + 20185088);    //  4,718,592  [1024][96]/layer
    short* Wo_t  = (short*)(wsb + 24903680);    //  1,966,080  [80][512]/layer
    short* W1_t  = (short*)(wsb + 26869760);    //    737,280  [160][96]/layer
    short* W2_t  = (short*)(wsb + 27607040);    //    614,400  [80][160]/layer
    short* lnx   = (short*)(wsb + 28221440);    //  1,572,864  [8192][96]

    static const int ATTN_LDS = 54272;
    hipFuncSetAttribute((const void*)attn2_kernel,
                        hipFuncAttributeMaxDynamicSharedMemorySize, ATTN_LDS);

    wconv_kernel<<<dim3(8, 2, 24), 256, 0, stream>>>(Wq,  Wq_t,  80, 512, 96);
    wconv_kernel<<<dim3(16, 2, 24), 256, 0, stream>>>(Wkv, Wkv_t, 80, 1024, 96);
    wconv_kernel<<<dim3(2, 8, 24), 256, 0, stream>>>(Wo,  Wo_t,  512, 80, 512);
    wconv_kernel<<<dim3(3, 2, 24), 256, 0, stream>>>(W1,  W1_t,  80, 160, 96);
    wconv_kernel<<<dim3(2, 3, 24), 256, 0, stream>>>(W2,  W2_t,  160, 80, 160);

    bias_kernel<<<4096, 256, 0, stream>>>(spatial_pos, edge_input, edge_emb,
                                          edge_dis_w, spatial_emb, biasb);
    node_emb_kernel<<<2560, 256, 0, stream>>>(x_nodes, indeg, outdeg,
                                              atom_emb, indeg_emb, outdeg_emb, x0);
    ln1_kernel<<<64, 256, 0, stream>>>(x0, ln1_g, ln1_b, lnx);

    for (int L = 0; L < DEPTH; ++L) {
        const float* xin  = (L & 1) ? x1 : x0;
        float*       xout = (L & 1) ? x0 : x1;
        attn2_kernel<<<512, 512, ATTN_LDS, stream>>>(
            lnx, biasb,
            Wq_t + (size_t)L * 512 * 96, Wkv_t + (size_t)L * 1024 * 96,
            obuf);
        const float* g1n  = (L < DEPTH - 1) ? (ln1_g + (L + 1) * DLAT) : nullptr;
        const float* be1n = (L < DEPTH - 1) ? (ln1_b + (L + 1) * DLAT) : nullptr;
        tail2_kernel<<<256, 512, 0, stream>>>(
            obuf, xin,
            Wo_t + (size_t)L * 80 * 512, bo + L * DLAT,
            ln2_g + L * DLAT, ln2_b + L * DLAT,
            W1_t + (size_t)L * 160 * 96, b1 + L * FFD,
            W2_t + (size_t)L * 80 * 160, b2 + L * DLAT,
            xout, g1n, be1n, lnx);
    }

    final_kernel<<<BDIM, 128, 0, stream>>>(x0, lnf_g, lnf_b, Wf, bf, (float*)d_out);
}